// Round 3
// baseline (14.979 us; speedup 1.0000x reference)
//
#include <hip/hip_runtime.h>

// out[n][d] = sum_k W[n][k] * F[k][d],  n in [0,128), d in [0,16384)
// F = [loss; prev_loss; params] (128 x 16384 fp32). W from 4096 edges:
// W[dst-S][src] += weight for dst >= S (S = 2 + P = 128).
//
// Single fused kernel. Block = (output row n, 2048-col chunk), bid = n*8+chunk
// so bid%8 == chunk -> one column slice per XCD (per-XCD L2 working set ~1 MB).
// Per block: scan edge list (L2-broadcast, 48 KB) into LDS Wrow, deterministic
// ballot compaction of ~16 nonzeros into (row-pointer, weight) pairs padded to
// a multiple of 8, then an unroll-8 float4 gather-FMA stream (16 loads in
// flight/wave) and non-temporal stores.

#define DCOLS 16384
#define VEC 8
#define CPB (256 * VEC)          // 2048 cols per block
#define CHUNKS (DCOLS / CPB)     // 8
#define MAXK 64                  // max nonzeros per row (Poisson(16); fixed data ~<40)

typedef float f4 __attribute__((ext_vector_type(4)));

__global__ __launch_bounds__(256) void fused_gather_gemm(
    const float* __restrict__ loss,
    const float* __restrict__ prev,
    const float* __restrict__ params,
    const float* __restrict__ weights,
    const int*   __restrict__ src,
    const int*   __restrict__ dst,
    float*       __restrict__ out,
    int E, int S) {

    __shared__ float               Wrow[128];
    __shared__ const float*        rowp[MAXK];
    __shared__ float               wv[MAXK];
    __shared__ unsigned long long  wmask[2];

    const int tid   = threadIdx.x;
    const int n     = blockIdx.x >> 3;
    const int chunk = blockIdx.x & (CHUNKS - 1);

    if (tid < S) Wrow[tid] = 0.0f;
    __syncthreads();

    // ---- scan edges: accumulate this row's W into LDS ----
    const int target = n + S;
    const int E4 = E & ~3;
    for (int e = tid * 4; e < E4; e += 256 * 4) {
        const int4 s4 = *reinterpret_cast<const int4*>(src + e);
        const int4 d4 = *reinterpret_cast<const int4*>(dst + e);
        const f4   w4 = *reinterpret_cast<const f4*>(weights + e);
        if (d4.x == target) atomicAdd(&Wrow[s4.x], w4.x);
        if (d4.y == target) atomicAdd(&Wrow[s4.y], w4.y);
        if (d4.z == target) atomicAdd(&Wrow[s4.z], w4.z);
        if (d4.w == target) atomicAdd(&Wrow[s4.w], w4.w);
    }
    for (int e = E4 + tid; e < E; e += 256) {
        if (dst[e] == target) atomicAdd(&Wrow[src[e]], weights[e]);
    }
    __syncthreads();

    // ---- deterministic ballot compaction (tids 0..S-1, 2 waves) ----
    if (tid < S) {
        const bool nz = (Wrow[tid] != 0.0f);
        const unsigned long long m = __ballot(nz);
        if ((tid & 63) == 0) wmask[tid >> 6] = m;
    }
    __syncthreads();

    const unsigned long long m0 = wmask[0], m1 = wmask[1];
    const int cnt    = __popcll(m0) + __popcll(m1);
    const int cntPad = (cnt + 7) & ~7;           // <= MAXK

    if (tid < S) {
        const unsigned long long m = (tid < 64) ? m0 : m1;
        const int lane = tid & 63;
        if ((m >> lane) & 1ULL) {
            const int pos = __popcll(m & ((1ULL << lane) - 1ULL))
                          + ((tid >= 64) ? __popcll(m0) : 0);
            rowp[pos] = (tid == 0) ? loss
                      : (tid == 1) ? prev
                      : params + (size_t)(tid - 2) * DCOLS;
            wv[pos] = Wrow[tid];
        }
    }
    if (tid >= cnt && tid < cntPad) {            // pad entries: real loads, zero weight
        rowp[tid] = loss;
        wv[tid]   = 0.0f;
    }
    __syncthreads();

    // ---- stream: unroll-8 gather-FMA over padded nonzero list ----
    const int col = chunk * CPB + tid * 4;       // first float4; second at +1024
    f4 a0 = {0.f, 0.f, 0.f, 0.f};
    f4 a1 = {0.f, 0.f, 0.f, 0.f};

    #pragma unroll 8
    for (int i = 0; i < cntPad; ++i) {
        const float* p = rowp[i];
        const float  w = wv[i];
        const f4 f0 = *reinterpret_cast<const f4*>(p + col);
        const f4 f1 = *reinterpret_cast<const f4*>(p + col + 1024);
        a0 = f0 * w + a0;
        a1 = f1 * w + a1;
    }

    float* o = out + (size_t)n * DCOLS + col;
    __builtin_nontemporal_store(a0, reinterpret_cast<f4*>(o));
    __builtin_nontemporal_store(a1, reinterpret_cast<f4*>(o + 1024));
}

extern "C" void kernel_launch(void* const* d_in, const int* in_sizes, int n_in,
                              void* d_out, int out_size, void* d_ws, size_t ws_size,
                              hipStream_t stream) {
    const float* loss    = (const float*)d_in[0];
    const float* prev    = (const float*)d_in[1];
    const float* params  = (const float*)d_in[2];
    const float* weights = (const float*)d_in[3];
    const int*   src     = (const int*)d_in[4];
    const int*   dst     = (const int*)d_in[5];
    float*       out     = (float*)d_out;

    const int E    = in_sizes[3];              // 4096
    const int P    = in_sizes[2] / DCOLS;      // 126
    const int S    = 2 + P;                    // 128
    const int nOut = out_size / DCOLS;         // 128

    fused_gather_gemm<<<nOut * CHUNKS, 256, 0, stream>>>(
        loss, prev, params, weights, src, dst, out, E, S);
}

// Round 4
// 14.012 us; speedup vs baseline: 1.0690x; 1.0690x over previous
//
#include <hip/hip_runtime.h>

// out[n][d] = sum_k W[n][k] * F[k][d],  n in [0,128), d in [0,16384)
// F = [loss; prev_loss; params] (128 x 16384 fp32). W from 4096 edges:
// W[dst-S][src] += weight for dst >= S (S = 2+126 = 128).
//
// Dense-MFMA formulation: 128x128x16384 GEMM, A = W (bf16), B = F (bf16),
// fp32 accumulate via v_mfma_f32_16x16x32_bf16. One block per 64-column
// slice (grid 256 = 1 block/CU): F slice read ONCE from HBM (kills the
// ~128 MB of L2 re-reads of the gather formulation). W built in LDS fp32
// from the edge list in two 64-row half-phases (keeps static LDS at 48 KB),
// then converted straight into per-wave A-register fragments. F staged as
// bf16 [col][k] with XOR-swizzled 16B granules for conflict-free
// ds_read_b128 B-fragments.

#define DCOLS 16384
#define SD    128          // K dim == M dim (S = 2+P = nOut)
#define HALF  64           // W rows per build phase
#define NB    64           // output cols per block

typedef float  f32x4  __attribute__((ext_vector_type(4)));
typedef short  bf16x8 __attribute__((ext_vector_type(8)));
typedef unsigned int u32x4 __attribute__((ext_vector_type(4)));

__device__ __forceinline__ unsigned int f2bf(float x) {
    unsigned int u = __builtin_bit_cast(unsigned int, x);
    return (u + 0x7FFFu + ((u >> 16) & 1u)) >> 16;   // RNE; inputs are finite
}

__device__ __forceinline__ const float* frow(int k, const float* loss,
                                             const float* prev,
                                             const float* params) {
    return (k == 0) ? loss : (k == 1) ? prev : params + (size_t)(k - 2) * DCOLS;
}

__global__ __launch_bounds__(256) void fused_edges_mfma(
    const float* __restrict__ loss, const float* __restrict__ prev,
    const float* __restrict__ params, const float* __restrict__ weights,
    const int* __restrict__ src, const int* __restrict__ dst,
    float* __restrict__ out, int E, int S)
{
    __shared__ __align__(16) float          Wf[HALF * SD];   // 32 KB, 32B-granule swizzle
    __shared__ __align__(16) unsigned short Ft[NB * SD];     // 16 KB, 16B-granule swizzle

    const int tid  = threadIdx.x;
    const int lane = tid & 63;
    const int wave = tid >> 6;
    const int lr   = lane & 15;      // row/col within a 16-tile
    const int kq   = lane >> 4;      // 0..3 quarter-wave
    const int col0 = blockIdx.x * NB;

    // ---------- stage F -> Ft: bf16 [c][k], granule g = (k>>3) ^ (c&7) ----------
    for (int t = tid; t < (SD / 2) * (NB / 4); t += 256) {   // 1024 tasks
        const int kp = t >> 4;            // k-pair 0..63
        const int c4 = t & 15;            // col quad 0..15 (low bits -> coalesced)
        const int k0 = kp * 2;
        const float* r0 = frow(k0,     loss, prev, params);
        const float* r1 = frow(k0 + 1, loss, prev, params);
        const f32x4 a = *reinterpret_cast<const f32x4*>(r0 + col0 + c4 * 4);
        const f32x4 b = *reinterpret_cast<const f32x4*>(r1 + col0 + c4 * 4);
        #pragma unroll
        for (int i = 0; i < 4; ++i) {
            const int c = c4 * 4 + i;
            const unsigned int v = f2bf(a[i]) | (f2bf(b[i]) << 16);
            const int g  = (kp >> 2) ^ (c & 7);
            const int by = c * 256 + g * 16 + (kp & 3) * 4;
            *reinterpret_cast<unsigned int*>(reinterpret_cast<char*>(Ft) + by) = v;
        }
    }
    // no barrier needed yet: Ft is first read only after the final barrier

    u32x4 areg[2][4];   // per-lane A fragments (8 bf16 each) — filled by owning wave

    #pragma unroll
    for (int ph = 0; ph < 2; ++ph) {
        __syncthreads();                       // Wf free to (re)initialize
        const f32x4 z = {0.f, 0.f, 0.f, 0.f};
        #pragma unroll
        for (int i = 0; i < (HALF * SD / 4) / 256; ++i)      // 8 x f32x4 per thread
            *reinterpret_cast<f32x4*>(Wf + (i * 256 + tid) * 4) = z;
        __syncthreads();

        // ---- edge scan: accumulate rows [S+ph*64, S+ph*64+64) into swizzled Wf ----
        const int lo = S + ph * HALF;
        const int E4 = E & ~3;
        for (int e = tid * 4; e < E4; e += 1024) {
            const int4  s4 = *reinterpret_cast<const int4*>(src + e);
            const int4  d4 = *reinterpret_cast<const int4*>(dst + e);
            const f32x4 w4 = *reinterpret_cast<const f32x4*>(weights + e);
            int r;
            r = d4.x - lo; if ((unsigned)r < HALF) atomicAdd(&Wf[r * SD + ((((s4.x >> 3) ^ (r & 7)) << 3) | (s4.x & 7))], w4.x);
            r = d4.y - lo; if ((unsigned)r < HALF) atomicAdd(&Wf[r * SD + ((((s4.y >> 3) ^ (r & 7)) << 3) | (s4.y & 7))], w4.y);
            r = d4.z - lo; if ((unsigned)r < HALF) atomicAdd(&Wf[r * SD + ((((s4.z >> 3) ^ (r & 7)) << 3) | (s4.z & 7))], w4.z);
            r = d4.w - lo; if ((unsigned)r < HALF) atomicAdd(&Wf[r * SD + ((((s4.w >> 3) ^ (r & 7)) << 3) | (s4.w & 7))], w4.w);
        }
        for (int e = E4 + tid; e < E; e += 256) {
            const int r = dst[e] - lo;
            if ((unsigned)r < HALF) {
                const int k = src[e];
                atomicAdd(&Wf[r * SD + ((((k >> 3) ^ (r & 7)) << 3) | (k & 7))], weights[e]);
            }
        }
        __syncthreads();

        // ---- waves {2ph, 2ph+1}: pull this half's A fragments into registers ----
        if ((wave >> 1) == ph) {
            const int wl = wave & 1;
            #pragma unroll
            for (int mt = 0; mt < 2; ++mt) {
                const int rr = wl * 32 + mt * 16 + lr;       // local row 0..63
                #pragma unroll
                for (int kt = 0; kt < 4; ++kt) {
                    const int g = (kt * 4 + kq) ^ (rr & 7);
                    const float* p = Wf + rr * SD + g * 8;   // 8 contiguous fp32 (one granule)
                    const f32x4 x = *reinterpret_cast<const f32x4*>(p);
                    const f32x4 y = *reinterpret_cast<const f32x4*>(p + 4);
                    u32x4 v;
                    v.x = f2bf(x[0]) | (f2bf(x[1]) << 16);
                    v.y = f2bf(x[2]) | (f2bf(x[3]) << 16);
                    v.z = f2bf(y[0]) | (f2bf(y[1]) << 16);
                    v.w = f2bf(y[2]) | (f2bf(y[3]) << 16);
                    areg[mt][kt] = v;
                }
            }
        }
    }
    __syncthreads();    // Ft staging + all A converts complete

    // ---------- MFMA: wave w -> out rows [w*32, w*32+32), cols [col0, col0+64) ----------
    f32x4 acc[2][4] = {};
    #pragma unroll
    for (int kt = 0; kt < 4; ++kt) {
        bf16x8 bf[4];
        #pragma unroll
        for (int nt = 0; nt < 4; ++nt) {
            const int c = nt * 16 + lr;
            const int g = (kt * 4 + kq) ^ (c & 7);
            bf[nt] = *reinterpret_cast<const bf16x8*>(Ft + c * SD + g * 8);
        }
        #pragma unroll
        for (int mt = 0; mt < 2; ++mt) {
            const bf16x8 af = __builtin_bit_cast(bf16x8, areg[mt][kt]);
            #pragma unroll
            for (int nt = 0; nt < 4; ++nt)
                acc[mt][nt] = __builtin_amdgcn_mfma_f32_16x16x32_bf16(
                    af, bf[nt], acc[mt][nt], 0, 0, 0);
        }
    }

    // ---------- store (C/D layout: col = lane&15, row = (lane>>4)*4 + reg) ----------
    #pragma unroll
    for (int mt = 0; mt < 2; ++mt) {
        const int nbase = wave * 32 + mt * 16 + kq * 4;
        #pragma unroll
        for (int nt = 0; nt < 4; ++nt) {
            const int d = col0 + nt * 16 + lr;
            #pragma unroll
            for (int r = 0; r < 4; ++r)
                out[(size_t)(nbase + r) * DCOLS + d] = acc[mt][nt][r];
        }
    }
}

extern "C" void kernel_launch(void* const* d_in, const int* in_sizes, int n_in,
                              void* d_out, int out_size, void* d_ws, size_t ws_size,
                              hipStream_t stream) {
    const float* loss    = (const float*)d_in[0];
    const float* prev    = (const float*)d_in[1];
    const float* params  = (const float*)d_in[2];
    const float* weights = (const float*)d_in[3];
    const int*   src     = (const int*)d_in[4];
    const int*   dst     = (const int*)d_in[5];
    float*       out     = (float*)d_out;

    const int E = in_sizes[3];              // 4096
    const int P = in_sizes[2] / DCOLS;      // 126
    const int S = 2 + P;                    // 128

    fused_edges_mfma<<<DCOLS / NB, 256, 0, stream>>>(
        loss, prev, params, weights, src, dst, out, E, S);
}